// Round 1
// baseline (933.748 us; speedup 1.0000x reference)
//
#include <hip/hip_runtime.h>

// LSTM (H=32), B=2048, T=1024, prefix-masked + mean pool + sigmoid classifier.
// 3 kernels: (1) lengths from mask, (2) one-block counting sort of batch
// indices by length, (3) main LSTM: 1024 waves, wave p runs sorted[p] then
// sorted[B-1-p] sequentially => every wave does ~L_min+L_max ~= T+1 steps.
//
// v2 changes (theory: VGPR_Count=80 proved weights were NOT register-resident;
// compiler re-fetched them in-loop from L1 every step):
//  - __launch_bounds__(64,1) + volatile-asm pin on all weight regs: forces
//    128 weight floats/lane to stay in VGPRs (no remat-by-reload possible).
//  - weights/accumulators packed as float2 -> v_pk_fma_f32 (halves FMA issue).
//  - row remap: lane l<32 holds (i,f) rows, l>=32 holds (g,o) rows; apply
//    nonlinearity first, then exchange via v_permlane32_swap_b32 + xor3
//    (exact, direction-proof) instead of 2x ds_bpermute on the serial chain.
//    Saves 2 of 5 transcendental chains per step; both lane halves compute
//    identical (c,h), so h stays valid on all 64 lanes.

typedef float v2f __attribute__((ext_vector_type(2)));

__device__ __forceinline__ float fast_sigmoid(float x) {
    return __builtin_amdgcn_rcpf(1.0f + __expf(-x));
}
__device__ __forceinline__ float fast_tanh(float x) {
    return fmaf(2.0f, fast_sigmoid(2.0f * x), -1.0f);
}
__device__ __forceinline__ float lane_bcast(float v, int srclane) {
    return __int_as_float(__builtin_amdgcn_readlane(__float_as_int(v), srclane));
}
__device__ __forceinline__ v2f splat2(float x) { v2f r; r.x = x; r.y = x; return r; }
__device__ __forceinline__ v2f fma2(v2f a, v2f b, v2f c) {
#if __has_builtin(__builtin_elementwise_fma)
    return __builtin_elementwise_fma(a, b, c);
#else
    v2f r; r.x = fmaf(a.x, b.x, c.x); r.y = fmaf(a.y, b.y, c.y); return r;
#endif
}
// Cross-half partner fetch (lane ^ 32), exact and swap-direction-proof:
// after v_permlane32_swap_b32 a,b (a=b=v), per lane {a,b} == {v, partner},
// so partner = a ^ b ^ v bitwise.
__device__ __forceinline__ float partner32(float v) {
    float a = v, b = v;
    asm("v_permlane32_swap_b32 %0, %1" : "+v"(a), "+v"(b));
    return __uint_as_float(__float_as_uint(a) ^ __float_as_uint(b) ^
                           __float_as_uint(v));
}

// ---- macro machinery: 64 named float2 weight registers (128 VGPRs) ----
#define R16A(M) M(0) M(1) M(2) M(3) M(4) M(5) M(6) M(7) \
                M(8) M(9) M(10) M(11) M(12) M(13) M(14) M(15)
#define R16B(M) M(16) M(17) M(18) M(19) M(20) M(21) M(22) M(23) \
                M(24) M(25) M(26) M(27) M(28) M(29) M(30) M(31)
#define R32(M) R16A(M) R16B(M)

#define DECLW(i) v2f wi_##i, wh_##i;
#define LOADW(i) wi_##i.x = w_ih[r032 + (i)]; wi_##i.y = w_ih[r132 + (i)]; \
                 wh_##i.x = w_hh[r032 + (i)]; wh_##i.y = w_hh[r132 + (i)];
// pin: asm-defined values cannot be rematerialized by reloading from memory
#define PINW(i) asm volatile("" : "+v"(wi_##i), "+v"(wh_##i));

// x-part FMAs (uses register `xq`, acc pairs ax0n/ax1n; .x=row r0, .y=row r1)
#define XP0(i) { const float xm = lane_bcast(xq, i); ax0n = fma2(splat2(xm), wi_##i, ax0n); }
#define XP1(i) { const float xm = lane_bcast(xq, i); ax1n = fma2(splat2(xm), wi_##i, ax1n); }
// h-part FMAs (uses register `h`, acc pairs ah0/ah1)
#define HP0(i) { const float hm = lane_bcast(h, i); ah0 = fma2(splat2(hm), wh_##i, ah0); }
#define HP1(i) { const float hm = lane_bcast(h, i); ah1 = fma2(splat2(hm), wh_##i, ah1); }

// ---- kernel 1: sequence lengths from prefix mask ----
__global__ __launch_bounds__(64)
void len_kernel(const float* __restrict__ mask, int* __restrict__ lens, int B, int T)
{
    const int b = blockIdx.x;
    if (b >= B) return;
    const int lane = threadIdx.x;
    const float4* m4 = (const float4*)(mask + (size_t)b * T);
    float s = 0.0f;
    for (int i = lane; i < (T >> 2); i += 64) {
        const float4 v = m4[i];
        s += (v.x + v.y) + (v.z + v.w);
    }
#pragma unroll
    for (int off = 32; off > 0; off >>= 1) s += __shfl_down(s, off, 64);
    if (lane == 0) lens[b] = (int)(s + 0.5f);
}

// ---- kernel 2: one-block counting sort (ascending length) ----
__global__ __launch_bounds__(1024)
void sort_kernel(const int* __restrict__ lens, int* __restrict__ sortedIdx, int B, int T)
{
    __shared__ int hist[1024];
    __shared__ int scan[1024];
    __shared__ int cur[1024];
    const int tid = threadIdx.x;
    if (tid < T) hist[tid] = 0;
    __syncthreads();
    for (int b = tid; b < B; b += blockDim.x)
        atomicAdd(&hist[lens[b] - 1], 1);
    __syncthreads();
    if (tid < T) scan[tid] = hist[tid];
    __syncthreads();
    for (int off = 1; off < T; off <<= 1) {          // Hillis-Steele inclusive
        int v = 0;
        if (tid >= off && tid < T) v = scan[tid - off];
        __syncthreads();
        if (tid < T) scan[tid] += v;
        __syncthreads();
    }
    if (tid < T) cur[tid] = scan[tid] - hist[tid];   // exclusive prefix
    __syncthreads();
    for (int b = tid; b < B; b += blockDim.x) {
        const int pos = atomicAdd(&cur[lens[b] - 1], 1);
        sortedIdx[pos] = b;
    }
}

// ---- kernel 3: main LSTM, 1 wave per complement-pair of sequences ----
__global__ __launch_bounds__(64, 1)
void lstm_main(const float* __restrict__ x,        // [B,T,32]
               const int* __restrict__ lens,       // [B]
               const int* __restrict__ sortedIdx,  // [B]
               const float* __restrict__ w_ih,     // [128,32]
               const float* __restrict__ w_hh,     // [128,32]
               const float* __restrict__ b_ih,     // [128]
               const float* __restrict__ b_hh,     // [128]
               const float* __restrict__ w_cls,    // [1,32]
               const float* __restrict__ b_cls,    // [1]
               float* __restrict__ out,            // pooled [B,32] ++ probs [B]
               int B, int T)
{
    const int p = blockIdx.x;                      // 0 .. B/2-1
    const int lane = threadIdx.x;
    const int lm = lane & 31;
    const int hi = lane >> 5;                      // 0: i/f rows, 1: g/o rows
    const bool lo = (hi == 0);
    const int r0 = lm + 64 * hi;                   // i-row (lo) / g-row (hi)
    const int r1 = r0 + 32;                        // f-row (lo) / o-row (hi)
    const int r032 = r0 * 32, r132 = r1 * 32;
    const int Tm1 = T - 1;

    R32(DECLW)
    R32(LOADW)
    R32(PINW)                                      // force VGPR residency

    v2f bias;
    bias.x = b_ih[r0] + b_hh[r0];
    bias.y = b_ih[r1] + b_hh[r1];
    // nonlinearity constants: lo lanes sigma(x); hi lanes (acc.x only):
    // tanh(x) = 2*sigma(2x) - 1
    const float kin  = lo ? 1.0f : 2.0f;
    const float koff = lo ? 0.0f : -1.0f;

    for (int s = 0; s < 2; ++s) {
        const int b = sortedIdx[s == 0 ? p : (B - 1 - p)];
        const int L = lens[b];
        const float* xb = x + (size_t)b * T * 32;

        float h = 0.0f, c = 0.0f, hsum = 0.0f;

        // prime: x-part of step 0
        float xq = xb[lm];                                     // x_0
        v2f ax0n = bias, ax1n = splat2(0.0f);
        R16A(XP0) R16B(XP1)
        v2f ax0c = ax0n, ax1c = ax1n;
        xq = xb[min(1, Tm1) * 32 + lm];                        // x_1

        for (int t = 0; t < L; ++t) {
            const float xn = xb[min(t + 2, Tm1) * 32 + lm];    // prefetch x_{t+2}
            // h-part of step t
            v2f ah0 = splat2(0.0f), ah1 = splat2(0.0f);
            R16A(HP0) R16B(HP1)
            const v2f acc = (ax0c + ah0) + (ax1c + ah1);
            // own two gates: lo lanes (sig_i, sig_f); hi lanes (tanh_g, sig_o)
            const float v0 = fmaf(kin, fast_sigmoid(kin * acc.x), koff);
            const float v1 = fast_sigmoid(acc.y);
            // partner's two gates from the other 32-lane half
            const float g0 = partner32(v0);
            const float g1 = partner32(v1);
            // every lane now has all four gates: i*g = v0*g0 on both halves
            const float fv = lo ? v1 : g1;                     // sig_f
            const float ov = lo ? g1 : v1;                     // sig_o
            c = fmaf(fv, c, v0 * g0);
            h = ov * fast_tanh(c);                             // valid all lanes
            hsum += h;
            // x-part of step t+1 (independent of h-chain -> fills gate latency)
            ax0n = bias; ax1n = splat2(0.0f);
            R16A(XP0) R16B(XP1)
            ax0c = ax0n; ax1c = ax1n;
            xq = xn;
        }

        const float Lf = (float)L;                 // L >= 1 always
        const float pooled = hsum / Lf;
        if (lane < 32) out[(size_t)b * 32 + lane] = pooled;

        float contrib = (lane < 32) ? pooled * w_cls[lane] : 0.0f;
#pragma unroll
        for (int off = 32; off > 0; off >>= 1)
            contrib += __shfl_down(contrib, off, 64);
        if (lane == 0)
            out[(size_t)B * 32 + b] = fast_sigmoid(contrib + b_cls[0]);
    }
}

extern "C" void kernel_launch(void* const* d_in, const int* in_sizes, int n_in,
                              void* d_out, int out_size, void* d_ws, size_t ws_size,
                              hipStream_t stream)
{
    const float* x     = (const float*)d_in[0];
    const float* mask  = (const float*)d_in[1];
    const float* w_ih  = (const float*)d_in[2];
    const float* w_hh  = (const float*)d_in[3];
    const float* b_ih  = (const float*)d_in[4];
    const float* b_hh  = (const float*)d_in[5];
    const float* w_cls = (const float*)d_in[6];
    const float* b_cls = (const float*)d_in[7];
    float* out = (float*)d_out;

    const int B = out_size / 33;        // pooled B*32 + probs B
    const int T = in_sizes[1] / B;      // mask is [B,T]

    int* lens = (int*)d_ws;
    int* sidx = lens + B;

    len_kernel<<<B, 64, 0, stream>>>(mask, lens, B, T);
    sort_kernel<<<1, 1024, 0, stream>>>(lens, sidx, B, T);
    lstm_main<<<B / 2, 64, 0, stream>>>(x, lens, sidx, w_ih, w_hh, b_ih, b_hh,
                                        w_cls, b_cls, out, B, T);
}

// Round 2
// 894.916 us; speedup vs baseline: 1.0434x; 1.0434x over previous
//
#include <hip/hip_runtime.h>

// LSTM (H=32), B=2048, T=1024, prefix-masked + mean pool + sigmoid classifier.
// 3 kernels: (1) lengths from mask, (2) one-block counting sort of batch
// indices by length, (3) main LSTM.
//
// v3 changes:
//  - TLP: 2048 blocks (one sequence per wave) instead of 1024 pair-blocks.
//    Round 1 showed 1 wave/SIMD (Occupancy 11.5%) with ~800 cyc/step of
//    unhidden stall. Complementary order (block k -> sorted[k], block
//    k+B/2 -> sorted[B-1-k]) pairs a short and a long sequence on the same
//    SIMD under the round-robin dispatch model (B/2 divisible by
//    8 XCDs * 32 CUs * 4 SIMDs), balancing per-SIMD work at ~T steps.
//  - amdgpu_waves_per_eu(2,2): round-1 postmortem concluded the allocator
//    spills the 128 pinned weight regs to AGPRs (VGPR_Count stuck at 80,
//    FETCH_SIZE rules out scratch) and pays ~128 v_accvgpr_read/step.
//    waves_per_eu is the attribute that actually feeds the allocator's
//    pressure target (launch_bounds' 2nd arg demonstrably does not);
//    (2,2) sets the unified budget to 256 regs — enough for the ~160 live.

typedef float v2f __attribute__((ext_vector_type(2)));

__device__ __forceinline__ float fast_sigmoid(float x) {
    return __builtin_amdgcn_rcpf(1.0f + __expf(-x));
}
__device__ __forceinline__ float fast_tanh(float x) {
    return fmaf(2.0f, fast_sigmoid(2.0f * x), -1.0f);
}
__device__ __forceinline__ float lane_bcast(float v, int srclane) {
    return __int_as_float(__builtin_amdgcn_readlane(__float_as_int(v), srclane));
}
__device__ __forceinline__ v2f splat2(float x) { v2f r; r.x = x; r.y = x; return r; }
__device__ __forceinline__ v2f fma2(v2f a, v2f b, v2f c) {
#if __has_builtin(__builtin_elementwise_fma)
    return __builtin_elementwise_fma(a, b, c);
#else
    v2f r; r.x = fmaf(a.x, b.x, c.x); r.y = fmaf(a.y, b.y, c.y); return r;
#endif
}
// Cross-half partner fetch (lane ^ 32), exact and swap-direction-proof:
// after v_permlane32_swap_b32 a,b (a=b=v), per lane {a,b} == {v, partner},
// so partner = a ^ b ^ v bitwise.
__device__ __forceinline__ float partner32(float v) {
    float a = v, b = v;
    asm("v_permlane32_swap_b32 %0, %1" : "+v"(a), "+v"(b));
    return __uint_as_float(__float_as_uint(a) ^ __float_as_uint(b) ^
                           __float_as_uint(v));
}

// ---- macro machinery: 64 named float2 weight registers (128 VGPRs) ----
#define R16A(M) M(0) M(1) M(2) M(3) M(4) M(5) M(6) M(7) \
                M(8) M(9) M(10) M(11) M(12) M(13) M(14) M(15)
#define R16B(M) M(16) M(17) M(18) M(19) M(20) M(21) M(22) M(23) \
                M(24) M(25) M(26) M(27) M(28) M(29) M(30) M(31)
#define R32(M) R16A(M) R16B(M)

#define DECLW(i) v2f wi_##i, wh_##i;
#define LOADW(i) wi_##i.x = w_ih[r032 + (i)]; wi_##i.y = w_ih[r132 + (i)]; \
                 wh_##i.x = w_hh[r032 + (i)]; wh_##i.y = w_hh[r132 + (i)];
// pin: asm-defined values cannot be rematerialized by reloading from memory
#define PINW(i) asm volatile("" : "+v"(wi_##i), "+v"(wh_##i));

// x-part FMAs (uses register `xq`, acc pairs ax0n/ax1n; .x=row r0, .y=row r1)
#define XP0(i) { const float xm = lane_bcast(xq, i); ax0n = fma2(splat2(xm), wi_##i, ax0n); }
#define XP1(i) { const float xm = lane_bcast(xq, i); ax1n = fma2(splat2(xm), wi_##i, ax1n); }
// h-part FMAs (uses register `h`, acc pairs ah0/ah1)
#define HP0(i) { const float hm = lane_bcast(h, i); ah0 = fma2(splat2(hm), wh_##i, ah0); }
#define HP1(i) { const float hm = lane_bcast(h, i); ah1 = fma2(splat2(hm), wh_##i, ah1); }

// ---- kernel 1: sequence lengths from prefix mask ----
__global__ __launch_bounds__(64)
void len_kernel(const float* __restrict__ mask, int* __restrict__ lens, int B, int T)
{
    const int b = blockIdx.x;
    if (b >= B) return;
    const int lane = threadIdx.x;
    const float4* m4 = (const float4*)(mask + (size_t)b * T);
    float s = 0.0f;
    for (int i = lane; i < (T >> 2); i += 64) {
        const float4 v = m4[i];
        s += (v.x + v.y) + (v.z + v.w);
    }
#pragma unroll
    for (int off = 32; off > 0; off >>= 1) s += __shfl_down(s, off, 64);
    if (lane == 0) lens[b] = (int)(s + 0.5f);
}

// ---- kernel 2: one-block counting sort (ascending length) ----
__global__ __launch_bounds__(1024)
void sort_kernel(const int* __restrict__ lens, int* __restrict__ sortedIdx, int B, int T)
{
    __shared__ int hist[1024];
    __shared__ int scan[1024];
    __shared__ int cur[1024];
    const int tid = threadIdx.x;
    if (tid < T) hist[tid] = 0;
    __syncthreads();
    for (int b = tid; b < B; b += blockDim.x)
        atomicAdd(&hist[lens[b] - 1], 1);
    __syncthreads();
    if (tid < T) scan[tid] = hist[tid];
    __syncthreads();
    for (int off = 1; off < T; off <<= 1) {          // Hillis-Steele inclusive
        int v = 0;
        if (tid >= off && tid < T) v = scan[tid - off];
        __syncthreads();
        if (tid < T) scan[tid] += v;
        __syncthreads();
    }
    if (tid < T) cur[tid] = scan[tid] - hist[tid];   // exclusive prefix
    __syncthreads();
    for (int b = tid; b < B; b += blockDim.x) {
        const int pos = atomicAdd(&cur[lens[b] - 1], 1);
        sortedIdx[pos] = b;
    }
}

// ---- kernel 3: main LSTM, 1 wave per sequence, complementary pairing ----
__global__ __launch_bounds__(64) __attribute__((amdgpu_waves_per_eu(2, 2)))
void lstm_main(const float* __restrict__ x,        // [B,T,32]
               const int* __restrict__ lens,       // [B]
               const int* __restrict__ sortedIdx,  // [B]
               const float* __restrict__ w_ih,     // [128,32]
               const float* __restrict__ w_hh,     // [128,32]
               const float* __restrict__ b_ih,     // [128]
               const float* __restrict__ b_hh,     // [128]
               const float* __restrict__ w_cls,    // [1,32]
               const float* __restrict__ b_cls,    // [1]
               float* __restrict__ out,            // pooled [B,32] ++ probs [B]
               int B, int T)
{
    const int i = blockIdx.x;                      // 0 .. B-1
    // complementary order: block k and block k+B/2 land on the same SIMD
    // under round-robin dispatch (B/2 = 1024 ≡ 0 mod XCD/CU/SIMD strides),
    // so pair them as (rank k, rank B-1-k): per-SIMD total ~T steps.
    const int half = B >> 1;
    const int sidx = (i < half) ? i : (B + half - 1 - i);
    const int lane = threadIdx.x;
    const int lm = lane & 31;
    const int hi = lane >> 5;                      // 0: i/f rows, 1: g/o rows
    const bool lo = (hi == 0);
    const int r0 = lm + 64 * hi;                   // i-row (lo) / g-row (hi)
    const int r1 = r0 + 32;                        // f-row (lo) / o-row (hi)
    const int r032 = r0 * 32, r132 = r1 * 32;
    const int Tm1 = T - 1;

    R32(DECLW)
    R32(LOADW)
    R32(PINW)                                      // forbid memory remat

    v2f bias;
    bias.x = b_ih[r0] + b_hh[r0];
    bias.y = b_ih[r1] + b_hh[r1];
    // nonlinearity constants: lo lanes sigma(x); hi lanes (acc.x only):
    // tanh(x) = 2*sigma(2x) - 1
    const float kin  = lo ? 1.0f : 2.0f;
    const float koff = lo ? 0.0f : -1.0f;

    const int b = sortedIdx[sidx];
    const int L = lens[b];
    const float* xb = x + (size_t)b * T * 32;

    float h = 0.0f, c = 0.0f, hsum = 0.0f;

    // prime: x-part of step 0
    float xq = xb[lm];                                     // x_0
    v2f ax0n = bias, ax1n = splat2(0.0f);
    R16A(XP0) R16B(XP1)
    v2f ax0c = ax0n, ax1c = ax1n;
    xq = xb[min(1, Tm1) * 32 + lm];                        // x_1

    for (int t = 0; t < L; ++t) {
        const float xn = xb[min(t + 2, Tm1) * 32 + lm];    // prefetch x_{t+2}
        // h-part of step t
        v2f ah0 = splat2(0.0f), ah1 = splat2(0.0f);
        R16A(HP0) R16B(HP1)
        const v2f acc = (ax0c + ah0) + (ax1c + ah1);
        // own two gates: lo lanes (sig_i, sig_f); hi lanes (tanh_g, sig_o)
        const float v0 = fmaf(kin, fast_sigmoid(kin * acc.x), koff);
        const float v1 = fast_sigmoid(acc.y);
        // partner's two gates from the other 32-lane half
        const float g0 = partner32(v0);
        const float g1 = partner32(v1);
        // every lane now has all four gates: i*g = v0*g0 on both halves
        const float fv = lo ? v1 : g1;                     // sig_f
        const float ov = lo ? g1 : v1;                     // sig_o
        c = fmaf(fv, c, v0 * g0);
        h = ov * fast_tanh(c);                             // valid all lanes
        hsum += h;
        // x-part of step t+1 (independent of h-chain -> fills gate latency)
        ax0n = bias; ax1n = splat2(0.0f);
        R16A(XP0) R16B(XP1)
        ax0c = ax0n; ax1c = ax1n;
        xq = xn;
    }

    const float Lf = (float)L;                 // L >= 1 always
    const float pooled = hsum / Lf;
    if (lane < 32) out[(size_t)b * 32 + lane] = pooled;

    float contrib = (lane < 32) ? pooled * w_cls[lane] : 0.0f;
#pragma unroll
    for (int off = 32; off > 0; off >>= 1)
        contrib += __shfl_down(contrib, off, 64);
    if (lane == 0)
        out[(size_t)B * 32 + b] = fast_sigmoid(contrib + b_cls[0]);
}

extern "C" void kernel_launch(void* const* d_in, const int* in_sizes, int n_in,
                              void* d_out, int out_size, void* d_ws, size_t ws_size,
                              hipStream_t stream)
{
    const float* x     = (const float*)d_in[0];
    const float* mask  = (const float*)d_in[1];
    const float* w_ih  = (const float*)d_in[2];
    const float* w_hh  = (const float*)d_in[3];
    const float* b_ih  = (const float*)d_in[4];
    const float* b_hh  = (const float*)d_in[5];
    const float* w_cls = (const float*)d_in[6];
    const float* b_cls = (const float*)d_in[7];
    float* out = (float*)d_out;

    const int B = out_size / 33;        // pooled B*32 + probs B
    const int T = in_sizes[1] / B;      // mask is [B,T]

    int* lens = (int*)d_ws;
    int* sidx = lens + B;

    len_kernel<<<B, 64, 0, stream>>>(mask, lens, B, T);
    sort_kernel<<<1, 1024, 0, stream>>>(lens, sidx, B, T);
    lstm_main<<<B, 64, 0, stream>>>(x, lens, sidx, w_ih, w_hh, b_ih, b_hh,
                                    w_cls, b_cls, out, B, T);
}